// Round 9
// baseline (871.325 us; speedup 1.0000x reference)
//
#include <hip/hip_runtime.h>
#include <hip/hip_bf16.h>

typedef __hip_bfloat16 bf16;
typedef short s16x8 __attribute__((ext_vector_type(8)));
typedef unsigned short u16x8 __attribute__((ext_vector_type(8)));
typedef float f32x4 __attribute__((ext_vector_type(4)));

#define T_TOK 2048
#define HDIM  2048
#define NEXP  64
#define IDIM  768
#define TOPK  8
#define OUT_OFF (T_TOK * HDIM)
#define NPAIR (T_TOK * TOPK)

#define WS_TOPK_IDX  0
#define WS_TOPK_W    (64 * 1024)
#define WS_PAIR_TOK  (128 * 1024)
#define WS_SLOT_OF   (192 * 1024)
#define WS_COUNTS    (256 * 1024)
#define WS_OFFSETS   (257 * 1024)
#define WS_CURSOR    (258 * 1024)
#define WS_H         (1024 * 1024)             // bf16 [NPAIR][IDIM]
#define WS_PARTIAL   (WS_H + (size_t)NPAIR * IDIM * 2)  // bf16 [NPAIR][HDIM]
#define WS_XB        WS_PARTIAL                // bf16 [T][H] (dead before partial written)

__device__ __forceinline__ float bf_to_f(unsigned short u) {
    return __uint_as_float(((unsigned int)u) << 16);
}
__device__ __forceinline__ unsigned short f2bf(float f) {
    unsigned int u = __float_as_uint(f);
    unsigned int r = (u + 0x7FFFu + ((u >> 16) & 1u)) >> 16;
    return (unsigned short)r;
}
__device__ __forceinline__ unsigned cvtpk(float lo, float hi) {
    unsigned r;
    asm("v_cvt_pk_bf16_f32 %0, %1, %2" : "=v"(r) : "v"(lo), "v"(hi));
    return r;
}

typedef const __attribute__((address_space(1))) unsigned int* gas_ptr;
typedef __attribute__((address_space(3))) unsigned int* las_ptr;
__device__ __forceinline__ void gload_lds16(const void* g, void* l) {
    __builtin_amdgcn_global_load_lds((gas_ptr)g, (las_ptr)l, 16, 0, 0);
}

// ---------------- kernel 0: x fp32 -> bf16 ----------------
__global__ __launch_bounds__(256) void xbf_kernel(const float* __restrict__ x,
                                                  unsigned short* __restrict__ xb) {
    int i = blockIdx.x * 256 + threadIdx.x;
    const float4* src = (const float4*)x + (size_t)i * 2;
    float4 a = src[0], b = src[1];
    u16x8 o;
    o[0] = f2bf(a.x); o[1] = f2bf(a.y); o[2] = f2bf(a.z); o[3] = f2bf(a.w);
    o[4] = f2bf(b.x); o[5] = f2bf(b.y); o[6] = f2bf(b.z); o[7] = f2bf(b.w);
    ((u16x8*)xb)[i] = o;
}

// ---------------- kernel 1: router logits ----------------
__global__ __launch_bounds__(256) void router_kernel(
    const float* __restrict__ x, const float* __restrict__ rw,
    float* __restrict__ logits) {
    int wave = threadIdx.x >> 6;
    int lane = threadIdx.x & 63;
    int t = blockIdx.x * 4 + wave;
    const float4* x4 = (const float4*)(x + (size_t)t * HDIM);
    float acc = 0.f;
    for (int h4 = 0; h4 < HDIM / 4; ++h4) {
        float4 xv = x4[h4];
        int h = h4 * 4;
        acc = fmaf(xv.x, rw[(h + 0) * NEXP + lane], acc);
        acc = fmaf(xv.y, rw[(h + 1) * NEXP + lane], acc);
        acc = fmaf(xv.z, rw[(h + 2) * NEXP + lane], acc);
        acc = fmaf(xv.w, rw[(h + 3) * NEXP + lane], acc);
    }
    logits[t * NEXP + lane] = acc;
}

// ---------------- kernel 2: softmax + top-8 ----------------
__global__ __launch_bounds__(64) void topk_kernel(
    const float* __restrict__ logits, int* __restrict__ topk_idx,
    float* __restrict__ topk_w, int* __restrict__ counts) {
    int t = blockIdx.x;
    int lane = threadIdx.x;
    float lg = logits[t * NEXP + lane];
    float mx = lg;
    for (int off = 32; off; off >>= 1) mx = fmaxf(mx, __shfl_xor(mx, off));
    float ex = expf(lg - mx);
    float sum = ex;
    for (int off = 32; off; off >>= 1) sum += __shfl_xor(sum, off);
    float prob = ex / sum;

    float pr = prob;
    float myv = 0.f;
    int myidx = 0;
    float ksum = 0.f;
    for (int k = 0; k < TOPK; ++k) {
        float v = pr;
        int idx = lane;
        for (int off = 32; off; off >>= 1) {
            float ov = __shfl_xor(v, off);
            int oi = __shfl_xor(idx, off);
            if (ov > v || (ov == v && oi < idx)) { v = ov; idx = oi; }
        }
        ksum += v;
        if (lane == k) { myidx = idx; myv = v; }
        if (lane == idx) pr = -1.f;
    }
    if (lane < TOPK) {
        topk_idx[t * TOPK + lane] = myidx;
        topk_w[t * TOPK + lane] = myv / ksum;
        atomicAdd(&counts[myidx], 1);
    }
}

// ---------------- kernel 3: scan ----------------
__global__ __launch_bounds__(64) void scan_kernel(
    const int* __restrict__ counts, int* __restrict__ offsets, int* __restrict__ cursor) {
    int lane = threadIdx.x;
    int c = counts[lane];
    int incl = c;
    for (int off = 1; off < 64; off <<= 1) {
        int tt = __shfl_up(incl, off);
        if (lane >= off) incl += tt;
    }
    offsets[lane] = incl - c;
    if (lane == 63) offsets[64] = incl;
    cursor[lane] = 0;
}

// ---------------- kernel 4: scatter ----------------
__global__ __launch_bounds__(256) void scatter_kernel(
    const int* __restrict__ topk_idx, const int* __restrict__ offsets,
    int* __restrict__ cursor, int* __restrict__ pair_token, int* __restrict__ slot_of) {
    int i = blockIdx.x * 256 + threadIdx.x;
    if (i >= NPAIR) return;
    int t = i >> 3;
    int e = topk_idx[i];
    int pos = atomicAdd(&cursor[e], 1);
    int slot = offsets[e] + pos;
    pair_token[slot] = t;
    slot_of[i] = slot;
}

// ===== MFMA grouped GEMMs: 512 thr, counted-vmcnt pipeline (depth-2 B) =====
#define BM   128
#define BKS  64
#define NKG  (HDIM / BKS)   // 32
#define NKD  (IDIM / BKS)   // 12
#define SB() __builtin_amdgcn_sched_barrier(0)

// One pipelined K-step for gateup. KS runtime, BV named reg set, P literal
// parity, DOA/DOB/WZ literal flags (issue A_{KS+1} / B_{KS+2} / wait-zero).
#define GU_STEP(KS, BV, P, DOA, DOB, WZ)                                      \
  {                                                                           \
    /* W: cvt B_(KS) regs -> bf16, ds_write into Bgu[P] */                    \
    uint4 w0, w1;                                                             \
    w0.x = cvtpk(BV[0].x, BV[1].x); w0.y = cvtpk(BV[2].x, BV[3].x);           \
    w0.z = cvtpk(BV[4].x, BV[5].x); w0.w = cvtpk(BV[6].x, BV[7].x);           \
    w1.x = cvtpk(BV[0].y, BV[1].y); w1.y = cvtpk(BV[2].y, BV[3].y);           \
    w1.z = cvtpk(BV[4].y, BV[5].y); w1.w = cvtpk(BV[6].y, BV[7].y);           \
    *(uint4*)&Bgu[P][brow0 * BKS + bslot] = w0;                               \
    *(uint4*)&Bgu[P][(brow0 + 1) * BKS + bslot] = w1;                         \
    SB();                                                                     \
    if (WZ) { asm volatile("s_waitcnt vmcnt(0) lgkmcnt(0)" ::: "memory"); }   \
    else    { asm volatile("s_waitcnt vmcnt(8) lgkmcnt(0)" ::: "memory"); }   \
    __builtin_amdgcn_s_barrier();                                             \
    SB();                                                                     \
    if (DOA) {                                                                \
      int h1 = ((KS) + 1) * BKS;                                              \
      gload_lds16(aq[0] + h1, &As[(P) ^ 1][tid * 8]);                         \
      gload_lds16(aq[1] + h1, &As[(P) ^ 1][(512 + tid) * 8]);                 \
      SB();                                                                   \
    }                                                                         \
    if (DOB) {                                                                \
      int h2 = ((KS) + 2) * BKS;                                              \
      _Pragma("unroll")                                                       \
      for (int i = 0; i < 8; ++i)                                             \
        BV[i] = *(const float2*)(bsrc + (size_t)(h2 + i) * IDIM);             \
    }                                                                         \
    /* C: MFMA on buffers P */                                                \
    _Pragma("unroll")                                                         \
    for (int kk = 0; kk < 2; ++kk) {                                          \
      int jk = kk * 4 + lg4;                                                  \
      s16x8 a[4], bg, bu;                                                     \
      _Pragma("unroll")                                                       \
      for (int mr = 0; mr < 4; ++mr) {                                        \
        int r = wr * 64 + mr * 16 + l15;                                      \
        a[mr] = *(const s16x8*)&As[P][r * BKS + ((jk ^ (r & 7)) * 8)];        \
      }                                                                       \
      int rg = wc * 16 + l15;                                                 \
      int ru = 64 + rg;                                                       \
      bg = *(const s16x8*)&Bgu[P][rg * BKS + ((jk ^ ((rg >> 1) & 7)) * 8)];   \
      bu = *(const s16x8*)&Bgu[P][ru * BKS + ((jk ^ ((ru >> 1) & 7)) * 8)];   \
      _Pragma("unroll")                                                       \
      for (int mr = 0; mr < 4; ++mr) {                                        \
        accg[mr] = __builtin_amdgcn_mfma_f32_16x16x32_bf16(a[mr], bg, accg[mr], 0, 0, 0); \
        accu[mr] = __builtin_amdgcn_mfma_f32_16x16x32_bf16(a[mr], bu, accu[mr], 0, 0, 0); \
      }                                                                       \
    }                                                                         \
  }

// ---------------- kernel 5: gateup ----------------
// 1536 blocks; (y=0,1) pair of same (e,ntile) co-located per XCD (id, id+8).
__global__ __launch_bounds__(512, 2) void gateup_mfma(
    const unsigned short* __restrict__ xb, const float* __restrict__ gate_w,
    const float* __restrict__ up_w, const int* __restrict__ offsets,
    const int* __restrict__ pair_token, unsigned short* __restrict__ hbuf) {
    int id = blockIdx.x;
    int b = id & 7, r9 = id >> 3;          // b ~ XCD
    int y = r9 & 1;
    int c = r9 >> 1;                       // 0..95
    int ntile = c >> 3;                    // 0..11
    int e = b + 8 * (c & 7);
    int off = offsets[e];
    int cnt = offsets[e + 1] - off;
    if (cnt <= 0) return;

    __shared__ unsigned short As[2][BM * BKS];      // 2 x 16 KB
    __shared__ unsigned short Bgu[2][BM * BKS];     // rows 0-63 gate, 64-127 up
    __shared__ int toks[BM];

    int tid = threadIdx.x;
    int lane = tid & 63;
    int wr = (tid >> 6) >> 2, wc = (tid >> 6) & 3;
    int l15 = lane & 15, lg4 = lane >> 4;

    int mat = tid >> 8;
    int t8 = tid & 255;
    int nI2 = t8 & 31, kC = t8 >> 5;
    int brow0 = mat * 64 + nI2 * 2;
    int bslot = (kC ^ (nI2 & 7)) * 8;
    const float* bsrc = (mat ? up_w : gate_w) + (size_t)e * HDIM * IDIM
                        + (size_t)(kC * 8) * IDIM + ntile * 64 + nI2 * 2;

    for (int mt = y; mt * BM < cnt; mt += 2) {
        int m0 = mt * BM;
        if (tid < BM) {
            int p = m0 + tid;
            toks[tid] = pair_token[off + (p < cnt ? p : 0)];
        }
        __syncthreads();   // toks ready + full drain between tiles
        const unsigned short* aq[2];
        #pragma unroll
        for (int q = 0; q < 2; ++q) {
            int row = q * 64 + (tid >> 3);
            aq[q] = xb + (size_t)toks[row] * HDIM + (((tid & 7) ^ (row & 7)) * 8);
        }
        f32x4 accg[4] = {};
        f32x4 accu[4] = {};

        // prologue: A_0 issue, then B_0 -> BvA, B_1 -> BvB (order pinned)
        gload_lds16(aq[0], &As[0][tid * 8]);
        gload_lds16(aq[1], &As[0][(512 + tid) * 8]);
        SB();
        float2 BvA[8], BvB[8];
        #pragma unroll
        for (int i = 0; i < 8; ++i)
            BvA[i] = *(const float2*)(bsrc + (size_t)i * IDIM);
        SB();
        #pragma unroll
        for (int i = 0; i < 8; ++i)
            BvB[i] = *(const float2*)(bsrc + (size_t)(BKS + i) * IDIM);
        SB();

        for (int ks = 0; ks < NKG - 2; ks += 2) {
            GU_STEP(ks, BvA, 0, 1, 1, 0);
            GU_STEP(ks + 1, BvB, 1, 1, 1, 0);
        }
        GU_STEP(NKG - 2, BvA, 0, 1, 0, 0);   // issues A_31, no B
        GU_STEP(NKG - 1, BvB, 1, 0, 0, 1);   // drain

        // epilogue: h = silu(g)*u
        int col = ntile * 64 + wc * 16 + l15;
        #pragma unroll
        for (int mr = 0; mr < 4; ++mr) {
            #pragma unroll
            for (int reg = 0; reg < 4; ++reg) {
                int rr = m0 + wr * 64 + mr * 16 + lg4 * 4 + reg;
                if (rr < cnt) {
                    float g = accg[mr][reg];
                    float u = accu[mr][reg];
                    float hv = (g / (1.f + __expf(-g))) * u;
                    hbuf[(size_t)(off + rr) * IDIM + col] = f2bf(hv);
                }
            }
        }
        __syncthreads();
    }
}

#define DN_STEP(KS, BV, P, DOA, DOB, WZ)                                      \
  {                                                                           \
    uint4 w0, w1;                                                             \
    w0.x = cvtpk(BV[0].x, BV[1].x); w0.y = cvtpk(BV[2].x, BV[3].x);           \
    w0.z = cvtpk(BV[4].x, BV[5].x); w0.w = cvtpk(BV[6].x, BV[7].x);           \
    w1.x = cvtpk(BV[0].y, BV[1].y); w1.y = cvtpk(BV[2].y, BV[3].y);           \
    w1.z = cvtpk(BV[4].y, BV[5].y); w1.w = cvtpk(BV[6].y, BV[7].y);           \
    *(uint4*)&Bd[P][brow0 * BKS + bslot] = w0;                                \
    *(uint4*)&Bd[P][(brow0 + 1) * BKS + bslot] = w1;                          \
    SB();                                                                     \
    if (WZ) { asm volatile("s_waitcnt vmcnt(0) lgkmcnt(0)" ::: "memory"); }   \
    else    { asm volatile("s_waitcnt vmcnt(8) lgkmcnt(0)" ::: "memory"); }   \
    __builtin_amdgcn_s_barrier();                                             \
    SB();                                                                     \
    if (DOA) {                                                                \
      int k1 = ((KS) + 1) * BKS;                                              \
      gload_lds16(aq[0] + k1, &As[(P) ^ 1][tid * 8]);                         \
      gload_lds16(aq[1] + k1, &As[(P) ^ 1][(512 + tid) * 8]);                 \
      SB();                                                                   \
    }                                                                         \
    if (DOB) {                                                                \
      int k2 = ((KS) + 2) * BKS;                                              \
      _Pragma("unroll")                                                       \
      for (int i = 0; i < 8; ++i)                                             \
        BV[i] = *(const float2*)(bsrc + (size_t)(k2 + i) * HDIM);             \
    }                                                                         \
    _Pragma("unroll")                                                         \
    for (int kk = 0; kk < 2; ++kk) {                                          \
      int jk = kk * 4 + lg4;                                                  \
      s16x8 a[4], bb[2];                                                      \
      _Pragma("unroll")                                                       \
      for (int mr = 0; mr < 4; ++mr) {                                        \
        int r = wr * 64 + mr * 16 + l15;                                      \
        a[mr] = *(const s16x8*)&As[P][r * BKS + ((jk ^ (r & 7)) * 8)];        \
      }                                                                       \
      _Pragma("unroll")                                                       \
      for (int nr = 0; nr < 2; ++nr) {                                        \
        int row = wc * 32 + nr * 16 + l15;                                    \
        bb[nr] = *(const s16x8*)&Bd[P][row * BKS + ((jk ^ ((row >> 1) & 7)) * 8)]; \
      }                                                                       \
      _Pragma("unroll")                                                       \
      for (int mr = 0; mr < 4; ++mr)                                          \
        _Pragma("unroll")                                                     \
        for (int nr = 0; nr < 2; ++nr)                                        \
          acc[mr][nr] = __builtin_amdgcn_mfma_f32_16x16x32_bf16(a[mr], bb[nr], acc[mr][nr], 0, 0, 0); \
    }                                                                         \
  }

// ---------------- kernel 6: down ----------------
// 2048 blocks; (y=0,1) pair of same (e,ntile) co-located per XCD.
__global__ __launch_bounds__(512, 2) void down_mfma(
    const unsigned short* __restrict__ hbuf, const float* __restrict__ down_w,
    const int* __restrict__ offsets, unsigned short* __restrict__ partial) {
    int id = blockIdx.x;
    int b = id & 7, r9 = id >> 3;
    int y = r9 & 1;
    int c = r9 >> 1;                       // 0..127
    int ntile = c >> 3;                    // 0..15
    int e = b + 8 * (c & 7);
    int off = offsets[e];
    int cnt = offsets[e + 1] - off;
    if (cnt <= 0) return;

    __shared__ unsigned short As[2][BM * BKS];      // 2 x 16 KB
    __shared__ unsigned short Bd[2][BM * BKS];      // [128n][64k] swz

    int tid = threadIdx.x;
    int lane = tid & 63;
    int wr = (tid >> 6) >> 2, wc = (tid >> 6) & 3;
    int l15 = lane & 15, lg4 = lane >> 4;

    int nI2 = tid & 63, kC = tid >> 6;
    int brow0 = nI2 * 2;
    int bslot = (kC ^ (nI2 & 7)) * 8;
    const float* bsrc = down_w + (size_t)e * IDIM * HDIM
                        + (size_t)(kC * 8) * HDIM + ntile * 128 + nI2 * 2;

    for (int mt = y; mt * BM < cnt; mt += 2) {
        int m0 = mt * BM;
        __syncthreads();   // full drain between tiles
        const unsigned short* aq[2];
        #pragma unroll
        for (int q = 0; q < 2; ++q) {
            int row = q * 64 + (tid >> 3);
            int rr = m0 + row;
            if (rr >= cnt) rr = cnt - 1;
            aq[q] = hbuf + (size_t)(off + rr) * IDIM + (((tid & 7) ^ (row & 7)) * 8);
        }
        f32x4 acc[4][2] = {};

        gload_lds16(aq[0], &As[0][tid * 8]);
        gload_lds16(aq[1], &As[0][(512 + tid) * 8]);
        SB();
        float2 BvA[8], BvB[8];
        #pragma unroll
        for (int i = 0; i < 8; ++i)
            BvA[i] = *(const float2*)(bsrc + (size_t)i * HDIM);
        SB();
        #pragma unroll
        for (int i = 0; i < 8; ++i)
            BvB[i] = *(const float2*)(bsrc + (size_t)(BKS + i) * HDIM);
        SB();

        for (int ks = 0; ks < NKD - 2; ks += 2) {
            DN_STEP(ks, BvA, 0, 1, 1, 0);
            DN_STEP(ks + 1, BvB, 1, 1, 1, 0);
        }
        DN_STEP(NKD - 2, BvA, 0, 1, 0, 0);
        DN_STEP(NKD - 1, BvB, 1, 0, 0, 1);

        #pragma unroll
        for (int mr = 0; mr < 4; ++mr)
            #pragma unroll
            for (int nr = 0; nr < 2; ++nr) {
                int col = ntile * 128 + wc * 32 + nr * 16 + l15;
                #pragma unroll
                for (int reg = 0; reg < 4; ++reg) {
                    int rr = m0 + wr * 64 + mr * 16 + lg4 * 4 + reg;
                    if (rr < cnt)
                        partial[(size_t)(off + rr) * HDIM + col] = f2bf(acc[mr][nr][reg]);
                }
            }
    }
}

// ---------------- kernel 7: weighted reduce ----------------
__global__ __launch_bounds__(256) void reduce_kernel(
    const unsigned short* __restrict__ partial, const int* __restrict__ slot_of,
    const float* __restrict__ topk_w, float* __restrict__ out) {
    int t = blockIdx.x;
    int j8 = threadIdx.x * 8;
    __shared__ int ss[8];
    __shared__ float sw[8];
    if (threadIdx.x < 8) {
        ss[threadIdx.x] = slot_of[t * TOPK + threadIdx.x];
        sw[threadIdx.x] = topk_w[t * TOPK + threadIdx.x];
    }
    __syncthreads();
    float acc[8] = {};
    #pragma unroll
    for (int k = 0; k < TOPK; ++k) {
        u16x8 v = *(const u16x8*)&partial[(size_t)ss[k] * HDIM + j8];
        float w = sw[k];
        #pragma unroll
        for (int i = 0; i < 8; ++i)
            acc[i] = fmaf(w, bf_to_f((unsigned short)v[i]), acc[i]);
    }
    float4 o0 = {acc[0], acc[1], acc[2], acc[3]};
    float4 o1 = {acc[4], acc[5], acc[6], acc[7]};
    *(float4*)&out[(size_t)t * HDIM + j8] = o0;
    *(float4*)&out[(size_t)t * HDIM + j8 + 4] = o1;
}

extern "C" void kernel_launch(void* const* d_in, const int* in_sizes, int n_in,
                              void* d_out, int out_size, void* d_ws, size_t ws_size,
                              hipStream_t stream) {
    const float* x  = (const float*)d_in[0];
    const float* rw = (const float*)d_in[1];
    const float* gw = (const float*)d_in[2];
    const float* uw = (const float*)d_in[3];
    const float* dw = (const float*)d_in[4];
    float* out = (float*)d_out;
    float* logits = out + OUT_OFF;

    char* ws = (char*)d_ws;
    int*   topk_idx   = (int*)(ws + WS_TOPK_IDX);
    float* topk_w     = (float*)(ws + WS_TOPK_W);
    int*   pair_token = (int*)(ws + WS_PAIR_TOK);
    int*   slot_of    = (int*)(ws + WS_SLOT_OF);
    int*   counts     = (int*)(ws + WS_COUNTS);
    int*   offsets    = (int*)(ws + WS_OFFSETS);
    int*   cursor     = (int*)(ws + WS_CURSOR);
    unsigned short* hbuf    = (unsigned short*)(ws + WS_H);
    unsigned short* partial = (unsigned short*)(ws + WS_PARTIAL);
    unsigned short* xb      = (unsigned short*)(ws + WS_XB);

    hipMemsetAsync(counts, 0, NEXP * sizeof(int), stream);
    xbf_kernel<<<T_TOK * HDIM / (256 * 8), 256, 0, stream>>>(x, xb);
    router_kernel<<<T_TOK / 4, 256, 0, stream>>>(x, rw, logits);
    topk_kernel<<<T_TOK, 64, 0, stream>>>(logits, topk_idx, topk_w, counts);
    scan_kernel<<<1, 64, 0, stream>>>(counts, offsets, cursor);
    scatter_kernel<<<NPAIR / 256, 256, 0, stream>>>(topk_idx, offsets, cursor, pair_token, slot_of);
    gateup_mfma<<<NEXP * 12 * 2, 512, 0, stream>>>(xb, gw, uw, offsets, pair_token, hbuf);
    down_mfma<<<NEXP * 16 * 2, 512, 0, stream>>>(hbuf, dw, offsets, partial);
    reduce_kernel<<<dim3(T_TOK, 1), 256, 0, stream>>>(partial, slot_of, topk_w, out);
}

// Round 10
// 714.151 us; speedup vs baseline: 1.2201x; 1.2201x over previous
//
#include <hip/hip_runtime.h>
#include <hip/hip_bf16.h>

typedef __hip_bfloat16 bf16;
typedef short s16x8 __attribute__((ext_vector_type(8)));
typedef unsigned short u16x8 __attribute__((ext_vector_type(8)));
typedef float f32x4 __attribute__((ext_vector_type(4)));

#define T_TOK 2048
#define HDIM  2048
#define NEXP  64
#define IDIM  768
#define TOPK  8
#define OUT_OFF (T_TOK * HDIM)
#define NPAIR (T_TOK * TOPK)

#define WS_TOPK_IDX  0
#define WS_TOPK_W    (64 * 1024)
#define WS_PAIR_TOK  (128 * 1024)
#define WS_SLOT_OF   (192 * 1024)
#define WS_COUNTS    (256 * 1024)
#define WS_OFFSETS   (257 * 1024)
#define WS_CURSOR    (258 * 1024)
#define WS_H         (1024 * 1024)             // bf16 [NPAIR][IDIM]
#define WS_PARTIAL   (WS_H + (size_t)NPAIR * IDIM * 2)  // bf16 [NPAIR][HDIM]
#define WS_XB        WS_PARTIAL                // bf16 [T][H] (dead before partial written)

__device__ __forceinline__ float bf_to_f(unsigned short u) {
    return __uint_as_float(((unsigned int)u) << 16);
}
__device__ __forceinline__ unsigned short f2bf(float f) {
    unsigned int u = __float_as_uint(f);
    unsigned int r = (u + 0x7FFFu + ((u >> 16) & 1u)) >> 16;
    return (unsigned short)r;
}
__device__ __forceinline__ unsigned cvtpk(float lo, float hi) {
    unsigned r;
    asm("v_cvt_pk_bf16_f32 %0, %1, %2" : "=v"(r) : "v"(lo), "v"(hi));
    return r;
}

typedef const __attribute__((address_space(1))) unsigned int* gas_ptr;
typedef __attribute__((address_space(3))) unsigned int* las_ptr;
__device__ __forceinline__ void gload_lds16(const void* g, void* l) {
    __builtin_amdgcn_global_load_lds((gas_ptr)g, (las_ptr)l, 16, 0, 0);
}

// ---------------- kernel 0: x fp32 -> bf16 ----------------
__global__ __launch_bounds__(256) void xbf_kernel(const float* __restrict__ x,
                                                  unsigned short* __restrict__ xb) {
    int i = blockIdx.x * 256 + threadIdx.x;
    const float4* src = (const float4*)x + (size_t)i * 2;
    float4 a = src[0], b = src[1];
    u16x8 o;
    o[0] = f2bf(a.x); o[1] = f2bf(a.y); o[2] = f2bf(a.z); o[3] = f2bf(a.w);
    o[4] = f2bf(b.x); o[5] = f2bf(b.y); o[6] = f2bf(b.z); o[7] = f2bf(b.w);
    ((u16x8*)xb)[i] = o;
}

// ---------------- kernel 1: router logits ----------------
__global__ __launch_bounds__(256) void router_kernel(
    const float* __restrict__ x, const float* __restrict__ rw,
    float* __restrict__ logits) {
    int wave = threadIdx.x >> 6;
    int lane = threadIdx.x & 63;
    int t = blockIdx.x * 4 + wave;
    const float4* x4 = (const float4*)(x + (size_t)t * HDIM);
    float acc = 0.f;
    for (int h4 = 0; h4 < HDIM / 4; ++h4) {
        float4 xv = x4[h4];
        int h = h4 * 4;
        acc = fmaf(xv.x, rw[(h + 0) * NEXP + lane], acc);
        acc = fmaf(xv.y, rw[(h + 1) * NEXP + lane], acc);
        acc = fmaf(xv.z, rw[(h + 2) * NEXP + lane], acc);
        acc = fmaf(xv.w, rw[(h + 3) * NEXP + lane], acc);
    }
    logits[t * NEXP + lane] = acc;
}

// ---------------- kernel 2: softmax + top-8 ----------------
__global__ __launch_bounds__(64) void topk_kernel(
    const float* __restrict__ logits, int* __restrict__ topk_idx,
    float* __restrict__ topk_w, int* __restrict__ counts) {
    int t = blockIdx.x;
    int lane = threadIdx.x;
    float lg = logits[t * NEXP + lane];
    float mx = lg;
    for (int off = 32; off; off >>= 1) mx = fmaxf(mx, __shfl_xor(mx, off));
    float ex = expf(lg - mx);
    float sum = ex;
    for (int off = 32; off; off >>= 1) sum += __shfl_xor(sum, off);
    float prob = ex / sum;

    float pr = prob;
    float myv = 0.f;
    int myidx = 0;
    float ksum = 0.f;
    for (int k = 0; k < TOPK; ++k) {
        float v = pr;
        int idx = lane;
        for (int off = 32; off; off >>= 1) {
            float ov = __shfl_xor(v, off);
            int oi = __shfl_xor(idx, off);
            if (ov > v || (ov == v && oi < idx)) { v = ov; idx = oi; }
        }
        ksum += v;
        if (lane == k) { myidx = idx; myv = v; }
        if (lane == idx) pr = -1.f;
    }
    if (lane < TOPK) {
        topk_idx[t * TOPK + lane] = myidx;
        topk_w[t * TOPK + lane] = myv / ksum;
        atomicAdd(&counts[myidx], 1);
    }
}

// ---------------- kernel 3: scan ----------------
__global__ __launch_bounds__(64) void scan_kernel(
    const int* __restrict__ counts, int* __restrict__ offsets, int* __restrict__ cursor) {
    int lane = threadIdx.x;
    int c = counts[lane];
    int incl = c;
    for (int off = 1; off < 64; off <<= 1) {
        int tt = __shfl_up(incl, off);
        if (lane >= off) incl += tt;
    }
    offsets[lane] = incl - c;
    if (lane == 63) offsets[64] = incl;
    cursor[lane] = 0;
}

// ---------------- kernel 4: scatter ----------------
__global__ __launch_bounds__(256) void scatter_kernel(
    const int* __restrict__ topk_idx, const int* __restrict__ offsets,
    int* __restrict__ cursor, int* __restrict__ pair_token, int* __restrict__ slot_of) {
    int i = blockIdx.x * 256 + threadIdx.x;
    if (i >= NPAIR) return;
    int t = i >> 3;
    int e = topk_idx[i];
    int pos = atomicAdd(&cursor[e], 1);
    int slot = offsets[e] + pos;
    pair_token[slot] = t;
    slot_of[i] = slot;
}

// ==== MFMA grouped GEMMs: BM=256 (weights once), BKS=32, 2 blocks/CU ====
#define BM   256
#define BKS  32
#define BROW 40                 // padded B LDS row (u16): 80 B
#define NKG  (HDIM / BKS)       // 64
#define NKD  (IDIM / BKS)       // 24

// ---------------- kernel 5: gateup ----------------
// 768 blocks (64e x 12nt, same-e on same XCD); 512 thr, 8 waves (4wr x 2wc);
// wave = 64m x 32i, both gate+up. K-step = 32.
__global__ __launch_bounds__(512, 4) void gateup_mfma(
    const unsigned short* __restrict__ xb, const float* __restrict__ gate_w,
    const float* __restrict__ up_w, const int* __restrict__ offsets,
    const int* __restrict__ pair_token, unsigned short* __restrict__ hbuf) {
    int id = blockIdx.x;
    int b = id & 7, rid = id >> 3;
    int ntile = rid % 12;                  // 64 i-cols each
    int e = b + 8 * (rid / 12);
    int off = offsets[e];
    int cnt = offsets[e + 1] - off;
    if (cnt <= 0) return;

    __shared__ unsigned short As[2][BM * BKS];     // 2 x 16 KB, linear [m][32] swz-chunks
    __shared__ unsigned short Bgu[2][128 * BROW];  // rows 0-63 gate, 64-127 up; 80B rows
    __shared__ int toks[BM];

    int tid = threadIdx.x;
    int lane = tid & 63;
    int wave = tid >> 6;
    int wr = wave >> 1, wc = wave & 1;
    int l15 = lane & 15, lg4 = lane >> 4;

    // B staging: 512 thr = 2 mat x 32 n-pair x 8 k-chunk (4k each)
    int mat = tid >> 8;
    int rem = tid & 255;
    int nI2 = rem & 31, kc8 = rem >> 5;
    int brow = mat * 64 + nI2 * 2;
    int bslot = (kc8 ^ (nI2 & 7)) * 4;     // u16 units, 8B slots
    const float* bsrc = (mat ? up_w : gate_w) + (size_t)e * HDIM * IDIM
                        + (size_t)(kc8 * 4) * IDIM + ntile * 64 + nI2 * 2;

    // A staging: cell = q*512+tid -> row=cell>>2, chunk c=cell&3 (8 elems each)
    int arowq = tid >> 2;                  // + q*128
    int ac = tid & 3;

    for (int mt = 0; mt * BM < cnt; ++mt) {
        int m0 = mt * BM;
        if (tid < BM) {
            int p = m0 + tid;
            toks[tid] = pair_token[off + (p < cnt ? p : cnt - 1)];
        }
        __syncthreads();
        const unsigned short* aq[2];
        #pragma unroll
        for (int q = 0; q < 2; ++q) {
            int row = q * 128 + arowq;
            int j2 = ac ^ (row & 3) ^ ((row >> 2) & 3);
            aq[q] = xb + (size_t)toks[row] * HDIM + j2 * 8;
        }
        f32x4 accg[4][2] = {};
        f32x4 accu[4][2] = {};

        // prologue: A_0 + B_0 regs
        gload_lds16(aq[0], &As[0][tid * 8]);
        gload_lds16(aq[1], &As[0][(512 + tid) * 8]);
        float2 Bv[4];
        #pragma unroll
        for (int i = 0; i < 4; ++i)
            Bv[i] = *(const float2*)(bsrc + (size_t)i * IDIM);

        for (int ks = 0; ks < NKG; ++ks) {
            int p = ks & 1;
            {   // cvt + 2x b64 writes (rows brow, brow+1)
                uint2 w0, w1;
                w0.x = cvtpk(Bv[0].x, Bv[1].x); w0.y = cvtpk(Bv[2].x, Bv[3].x);
                w1.x = cvtpk(Bv[0].y, Bv[1].y); w1.y = cvtpk(Bv[2].y, Bv[3].y);
                *(uint2*)&Bgu[p][brow * BROW + bslot] = w0;
                *(uint2*)&Bgu[p][(brow + 1) * BROW + bslot] = w1;
            }
            __syncthreads();   // drains A_ks gloads + B_ks writes
            if (ks + 1 < NKG) {
                int h1 = (ks + 1) * BKS;
                gload_lds16(aq[0] + h1, &As[p ^ 1][tid * 8]);
                gload_lds16(aq[1] + h1, &As[p ^ 1][(512 + tid) * 8]);
                #pragma unroll
                for (int i = 0; i < 4; ++i)
                    Bv[i] = *(const float2*)(bsrc + (size_t)((ks + 1) * BKS + i) * IDIM);
            }
            // MFMA on buffers p (one mfma per frag: K=32)
            s16x8 a[4];
            #pragma unroll
            for (int mr = 0; mr < 4; ++mr) {
                int r = wr * 64 + mr * 16 + l15;
                int sa = lg4 ^ (r & 3) ^ ((r >> 2) & 3);
                a[mr] = *(const s16x8*)&As[p][r * BKS + sa * 8];
            }
            #pragma unroll
            for (int nr = 0; nr < 2; ++nr) {
                int ng = wc * 32 + nr * 16 + l15;
                int s0 = ((2 * lg4) ^ ((ng >> 1) & 7)) * 4;
                int s1 = ((2 * lg4 + 1) ^ ((ng >> 1) & 7)) * 4;
                s16x8 bg, bu;
                *(uint2*)&bg = *(const uint2*)&Bgu[p][ng * BROW + s0];
                *((uint2*)&bg + 1) = *(const uint2*)&Bgu[p][ng * BROW + s1];
                *(uint2*)&bu = *(const uint2*)&Bgu[p][(64 + ng) * BROW + s0];
                *((uint2*)&bu + 1) = *(const uint2*)&Bgu[p][(64 + ng) * BROW + s1];
                #pragma unroll
                for (int mr = 0; mr < 4; ++mr) {
                    accg[mr][nr] = __builtin_amdgcn_mfma_f32_16x16x32_bf16(a[mr], bg, accg[mr][nr], 0, 0, 0);
                    accu[mr][nr] = __builtin_amdgcn_mfma_f32_16x16x32_bf16(a[mr], bu, accu[mr][nr], 0, 0, 0);
                }
            }
        }

        // epilogue: h = silu(g)*u
        #pragma unroll
        for (int mr = 0; mr < 4; ++mr)
            #pragma unroll
            for (int nr = 0; nr < 2; ++nr) {
                int col = ntile * 64 + wc * 32 + nr * 16 + l15;
                #pragma unroll
                for (int reg = 0; reg < 4; ++reg) {
                    int r = m0 + wr * 64 + mr * 16 + lg4 * 4 + reg;
                    if (r < cnt) {
                        float g = accg[mr][nr][reg];
                        float u = accu[mr][nr][reg];
                        float hv = (g / (1.f + __expf(-g))) * u;
                        hbuf[(size_t)(off + r) * IDIM + col] = f2bf(hv);
                    }
                }
            }
        __syncthreads();
    }
}

// ---------------- kernel 6: down ----------------
// 1024 blocks (64e x 16nt); 512 thr, 8 waves (4wr x 2wc); wave = 64m x 64n.
__global__ __launch_bounds__(512, 4) void down_mfma(
    const unsigned short* __restrict__ hbuf, const float* __restrict__ down_w,
    const int* __restrict__ offsets, unsigned short* __restrict__ partial) {
    int id = blockIdx.x;
    int b = id & 7, rid = id >> 3;
    int ntile = rid % 16;                  // 128 h-cols each
    int e = b + 8 * (rid / 16);
    int off = offsets[e];
    int cnt = offsets[e + 1] - off;
    if (cnt <= 0) return;

    __shared__ unsigned short As[2][BM * BKS];     // 2 x 16 KB
    __shared__ unsigned short Bd[2][128 * BROW];   // 128 n-rows, 80B rows

    int tid = threadIdx.x;
    int lane = tid & 63;
    int wave = tid >> 6;
    int wr = wave >> 1, wc = wave & 1;
    int l15 = lane & 15, lg4 = lane >> 4;

    // B staging: 512 thr = 64 n-pair x 8 k-chunk (4k each)
    int nI2 = tid & 63, kc8 = tid >> 6;
    int brow = nI2 * 2;
    int bslot = (kc8 ^ (nI2 & 7)) * 4;
    const float* bsrc = down_w + (size_t)e * IDIM * HDIM
                        + (size_t)(kc8 * 4) * HDIM + ntile * 128 + nI2 * 2;

    int arowq = tid >> 2;
    int ac = tid & 3;

    for (int mt = 0; mt * BM < cnt; ++mt) {
        int m0 = mt * BM;
        __syncthreads();   // LDS reuse guard
        const unsigned short* aq[2];
        #pragma unroll
        for (int q = 0; q < 2; ++q) {
            int row = q * 128 + arowq;
            int rr = m0 + row;
            if (rr >= cnt) rr = cnt - 1;
            int j2 = ac ^ (row & 3) ^ ((row >> 2) & 3);
            aq[q] = hbuf + (size_t)(off + rr) * IDIM + j2 * 8;
        }
        f32x4 acc[4][4] = {};

        gload_lds16(aq[0], &As[0][tid * 8]);
        gload_lds16(aq[1], &As[0][(512 + tid) * 8]);
        float2 Bv[4];
        #pragma unroll
        for (int i = 0; i < 4; ++i)
            Bv[i] = *(const float2*)(bsrc + (size_t)i * HDIM);

        for (int ks = 0; ks < NKD; ++ks) {
            int p = ks & 1;
            {
                uint2 w0, w1;
                w0.x = cvtpk(Bv[0].x, Bv[1].x); w0.y = cvtpk(Bv[2].x, Bv[3].x);
                w1.x = cvtpk(Bv[0].y, Bv[1].y); w1.y = cvtpk(Bv[2].y, Bv[3].y);
                *(uint2*)&Bd[p][brow * BROW + bslot] = w0;
                *(uint2*)&Bd[p][(brow + 1) * BROW + bslot] = w1;
            }
            __syncthreads();
            if (ks + 1 < NKD) {
                int k1 = (ks + 1) * BKS;
                gload_lds16(aq[0] + k1, &As[p ^ 1][tid * 8]);
                gload_lds16(aq[1] + k1, &As[p ^ 1][(512 + tid) * 8]);
                #pragma unroll
                for (int i = 0; i < 4; ++i)
                    Bv[i] = *(const float2*)(bsrc + (size_t)(k1 + i) * HDIM);
            }
            s16x8 a[4];
            #pragma unroll
            for (int mr = 0; mr < 4; ++mr) {
                int r = wr * 64 + mr * 16 + l15;
                int sa = lg4 ^ (r & 3) ^ ((r >> 2) & 3);
                a[mr] = *(const s16x8*)&As[p][r * BKS + sa * 8];
            }
            #pragma unroll
            for (int nr = 0; nr < 4; ++nr) {
                int n = wc * 64 + nr * 16 + l15;
                int s0 = ((2 * lg4) ^ ((n >> 1) & 7)) * 4;
                int s1 = ((2 * lg4 + 1) ^ ((n >> 1) & 7)) * 4;
                s16x8 bb;
                *(uint2*)&bb = *(const uint2*)&Bd[p][n * BROW + s0];
                *((uint2*)&bb + 1) = *(const uint2*)&Bd[p][n * BROW + s1];
                #pragma unroll
                for (int mr = 0; mr < 4; ++mr)
                    acc[mr][nr] = __builtin_amdgcn_mfma_f32_16x16x32_bf16(a[mr], bb, acc[mr][nr], 0, 0, 0);
            }
        }

        #pragma unroll
        for (int mr = 0; mr < 4; ++mr)
            #pragma unroll
            for (int nr = 0; nr < 4; ++nr) {
                int col = ntile * 128 + wc * 64 + nr * 16 + l15;
                #pragma unroll
                for (int reg = 0; reg < 4; ++reg) {
                    int r = m0 + wr * 64 + mr * 16 + lg4 * 4 + reg;
                    if (r < cnt)
                        partial[(size_t)(off + r) * HDIM + col] = f2bf(acc[mr][nr][reg]);
                }
            }
        __syncthreads();
    }
}

// ---------------- kernel 7: weighted reduce ----------------
__global__ __launch_bounds__(256) void reduce_kernel(
    const unsigned short* __restrict__ partial, const int* __restrict__ slot_of,
    const float* __restrict__ topk_w, float* __restrict__ out) {
    int t = blockIdx.x;
    int j8 = threadIdx.x * 8;
    __shared__ int ss[8];
    __shared__ float sw[8];
    if (threadIdx.x < 8) {
        ss[threadIdx.x] = slot_of[t * TOPK + threadIdx.x];
        sw[threadIdx.x] = topk_w[t * TOPK + threadIdx.x];
    }
    __syncthreads();
    float acc[8] = {};
    #pragma unroll
    for (int k = 0; k < TOPK; ++k) {
        u16x8 v = *(const u16x8*)&partial[(size_t)ss[k] * HDIM + j8];
        float w = sw[k];
        #pragma unroll
        for (int i = 0; i < 8; ++i)
            acc[i] = fmaf(w, bf_to_f((unsigned short)v[i]), acc[i]);
    }
    float4 o0 = {acc[0], acc[1], acc[2], acc[3]};
    float4 o1 = {acc[4], acc[5], acc[6], acc[7]};
    *(float4*)&out[(size_t)t * HDIM + j8] = o0;
    *(float4*)&out[(size_t)t * HDIM + j8 + 4] = o1;
}

extern "C" void kernel_launch(void* const* d_in, const int* in_sizes, int n_in,
                              void* d_out, int out_size, void* d_ws, size_t ws_size,
                              hipStream_t stream) {
    const float* x  = (const float*)d_in[0];
    const float* rw = (const float*)d_in[1];
    const float* gw = (const float*)d_in[2];
    const float* uw = (const float*)d_in[3];
    const float* dw = (const float*)d_in[4];
    float* out = (float*)d_out;
    float* logits = out + OUT_OFF;

    char* ws = (char*)d_ws;
    int*   topk_idx   = (int*)(ws + WS_TOPK_IDX);
    float* topk_w     = (float*)(ws + WS_TOPK_W);
    int*   pair_token = (int*)(ws + WS_PAIR_TOK);
    int*   slot_of    = (int*)(ws + WS_SLOT_OF);
    int*   counts     = (int*)(ws + WS_COUNTS);
    int*   offsets    = (int*)(ws + WS_OFFSETS);
    int*   cursor     = (int*)(ws + WS_CURSOR);
    unsigned short* hbuf    = (unsigned short*)(ws + WS_H);
    unsigned short* partial = (unsigned short*)(ws + WS_PARTIAL);
    unsigned short* xb      = (unsigned short*)(ws + WS_XB);

    hipMemsetAsync(counts, 0, NEXP * sizeof(int), stream);
    xbf_kernel<<<T_TOK * HDIM / (256 * 8), 256, 0, stream>>>(x, xb);
    router_kernel<<<T_TOK / 4, 256, 0, stream>>>(x, rw, logits);
    topk_kernel<<<T_TOK, 64, 0, stream>>>(logits, topk_idx, topk_w, counts);
    scan_kernel<<<1, 64, 0, stream>>>(counts, offsets, cursor);
    scatter_kernel<<<NPAIR / 256, 256, 0, stream>>>(topk_idx, offsets, cursor, pair_token, slot_of);
    gateup_mfma<<<NEXP * 12, 512, 0, stream>>>(xb, gw, uw, offsets, pair_token, hbuf);
    down_mfma<<<NEXP * 16, 512, 0, stream>>>(hbuf, dw, offsets, partial);
    reduce_kernel<<<dim3(T_TOK, 1), 256, 0, stream>>>(partial, slot_of, topk_w, out);
}